// Round 2
// baseline (993.637 us; speedup 1.0000x reference)
//
#include <hip/hip_runtime.h>
#include <hip/hip_bf16.h>
#include <stdint.h>

#define NN 40000
#define EE 640000
#define GG 256
#define FFE 9
#define HH 128

typedef __bf16 bf16;
typedef __bf16 bf16x8 __attribute__((ext_vector_type(8)));
typedef float f32x4 __attribute__((ext_vector_type(4)));

__device__ __forceinline__ f32x4 mfma16(bf16x8 a, bf16x8 b, f32x4 c){
  return __builtin_amdgcn_mfma_f32_16x16x32_bf16(a, b, c, 0, 0, 0);
}
// fast silu: v_rcp instead of precise f32 division (bf16-accuracy is plenty)
__device__ __forceinline__ float silu_f(float x){
  return x * __builtin_amdgcn_rcpf(1.0f + __expf(-x));
}
// byte-offset XOR swizzle for [row][256B] LDS tiles (T2 pattern)
__device__ __forceinline__ int swz(int row, int cb){
  return row*256 + (cb ^ ((row & 7) << 4));
}

// ---------------- weight prep: f32 [k][n] -> bf16 [n][k] ----------------
__global__ __launch_bounds__(256) void k_transpose_bf16(
    const float* __restrict__ src, bf16* __restrict__ dst,
    int R, int C, long sls, long dls)
{
  int l = blockIdx.y;
  int idx = blockIdx.x*256 + threadIdx.x;
  if (idx >= R*C) return;
  int n = idx / R, k = idx % R;
  dst[(long)l*dls + (long)n*R + k] = (bf16)src[(long)l*sls + (long)k*C + n];
}

__global__ __launch_bounds__(256) void k_bcat(const float* __restrict__ b1, float* __restrict__ bcat){
  int l = blockIdx.x, t = threadIdx.x;
  bcat[l*256 + t] = (t < 128) ? b1[l*128 + t] : 0.0f;
}

// ---------------- embedding: h = x @ emb_w + emb_b (f32 + bf16 copies) ----------------
__global__ __launch_bounds__(256) void k_emb(
    const float* __restrict__ x, const float* __restrict__ w,
    const float* __restrict__ b, float* __restrict__ h, bf16* __restrict__ hb)
{
  int idx = blockIdx.x*256 + threadIdx.x;
  int n = idx >> 7, f = idx & 127;
  float s = b[f];
  const float* xr = x + n*FFE;
  #pragma unroll
  for (int k=0;k<FFE;++k) s += xr[k]*w[k*HH + f];
  h[idx] = s;
  hb[idx] = (bf16)s;
}

// ---------------- counting sort by dst ----------------
__global__ __launch_bounds__(256) void k_hist(const int* __restrict__ dst, int* __restrict__ cnt){
  int e = blockIdx.x*256 + threadIdx.x;
  if (e < EE) atomicAdd(&cnt[dst[e]], 1);
}

__global__ __launch_bounds__(1024) void k_scan(const int* __restrict__ cnt, int* __restrict__ cursor, int n){
  __shared__ int s_wsum[16];
  __shared__ int s_run;
  int tid = threadIdx.x, lane = tid & 63, wv = tid >> 6;
  if (tid == 0) s_run = 0;
  __syncthreads();
  for (int base=0; base<n; base+=4096){
    int i = base + tid*4;
    int c0 = (i  <n)? cnt[i  ] : 0;
    int c1 = (i+1<n)? cnt[i+1] : 0;
    int c2 = (i+2<n)? cnt[i+2] : 0;
    int c3 = (i+3<n)? cnt[i+3] : 0;
    int t0 = c0, t1 = t0+c1, t2 = t1+c2, t3 = t2+c3;
    int x = t3;
    #pragma unroll
    for (int off=1; off<64; off<<=1){ int t = __shfl_up(x, off); if (lane>=off) x += t; }
    if (lane==63) s_wsum[wv] = x;
    __syncthreads();
    if (wv==0 && lane<16){
      int y = s_wsum[lane];
      #pragma unroll
      for (int off=1; off<16; off<<=1){ int t = __shfl_up(y, off, 16); if (lane>=off) y += t; }
      s_wsum[lane] = y;
    }
    __syncthreads();
    int woff = wv ? s_wsum[wv-1] : 0;
    int run = s_run;
    int eb = run + woff + x - t3;
    if (i  <n) cursor[i  ] = eb;
    if (i+1<n) cursor[i+1] = eb + t0;
    if (i+2<n) cursor[i+2] = eb + t1;
    if (i+3<n) cursor[i+3] = eb + t2;
    __syncthreads();
    if (tid==0) s_run = run + s_wsum[15];
    __syncthreads();
  }
}

__global__ __launch_bounds__(256) void k_scatter(
    const int* __restrict__ ei, const float* __restrict__ pos,
    int* __restrict__ cursor, int4* __restrict__ rec)
{
  int e = blockIdx.x*256 + threadIdx.x;
  if (e >= EE) return;
  int s = ei[e], d = ei[EE + e];
  int p = atomicAdd(&cursor[d], 1);
  float dx = pos[d*3+0]-pos[s*3+0];
  float dy = pos[d*3+1]-pos[s*3+1];
  float dz = pos[d*3+2]-pos[s*3+2];
  int4 rc; rc.x = s; rc.y = d; rc.z = __float_as_int(sqrtf(dx*dx+dy*dy+dz*dz)); rc.w = 0;
  rec[p] = rc;
}

// ---------------- generic 64x64-tile bf16 MFMA GEMM ----------------
// out = act(A @ WT' + bias) (+resid); WT stored [Nw][KTOT] bf16.
// A: first K1 cols from a1 (bf16 if A1BF else f32), rest from a2 (f32).
template<int KTOT, int K1, int ACT, bool A1BF, bool BIAS, bool RESID, bool OBF, bool OF>
__global__ __launch_bounds__(256) void k_gemm(
    const void* __restrict__ a1v, const float* __restrict__ a2,
    const bf16* __restrict__ wt, const float* __restrict__ bias,
    const float* __restrict__ resid, bf16* __restrict__ outb,
    float* __restrict__ outf, int Nw)
{
  constexpr int LDK = 136;
  __shared__ bf16 s_a[64*LDK];
  __shared__ bf16 s_w[64*LDK];
  int tid = threadIdx.x, lane = tid & 63, w = tid >> 6;
  int m0 = blockIdx.x*64, n0 = blockIdx.y*64;
  int wm = (w>>1)*32, wn = (w&1)*32;
  f32x4 acc[2][2];
  #pragma unroll
  for (int i=0;i<2;++i)
    #pragma unroll
    for (int j=0;j<2;++j)
      #pragma unroll
      for (int r=0;r<4;++r) acc[i][j][r]=0.f;
  int rsel = lane & 15, ksel = (lane>>4)*8;

  for (int kh=0; kh<KTOT; kh+=128){
    #pragma unroll
    for (int it=0; it<4; ++it){
      int idx = tid + it*256;
      int row = idx >> 4, col = (idx & 15)*8;
      int gc = kh + col;
      bf16x8 vv;
      if (gc < K1){
        if (A1BF){
          vv = *(const bf16x8*)((const bf16*)a1v + (size_t)(m0+row)*K1 + gc);
        } else {
          const float* srcp = (const float*)a1v + (size_t)(m0+row)*K1 + gc;
          f32x4 u0 = *(const f32x4*)srcp;
          f32x4 u1 = *(const f32x4*)(srcp+4);
          vv[0]=(bf16)u0[0]; vv[1]=(bf16)u0[1]; vv[2]=(bf16)u0[2]; vv[3]=(bf16)u0[3];
          vv[4]=(bf16)u1[0]; vv[5]=(bf16)u1[1]; vv[6]=(bf16)u1[2]; vv[7]=(bf16)u1[3];
        }
      } else {
        const float* srcp = a2 + (size_t)(m0+row)*(KTOT-K1) + (gc-K1);
        f32x4 u0 = *(const f32x4*)srcp;
        f32x4 u1 = *(const f32x4*)(srcp+4);
        vv[0]=(bf16)u0[0]; vv[1]=(bf16)u0[1]; vv[2]=(bf16)u0[2]; vv[3]=(bf16)u0[3];
        vv[4]=(bf16)u1[0]; vv[5]=(bf16)u1[1]; vv[6]=(bf16)u1[2]; vv[7]=(bf16)u1[3];
      }
      *(bf16x8*)&s_a[row*LDK + col] = vv;
      *(bf16x8*)&s_w[row*LDK + col] = *(const bf16x8*)(wt + (size_t)(n0+row)*KTOT + gc);
    }
    __syncthreads();
    #pragma unroll
    for (int ks=0; ks<4; ++ks){
      int kb = ks*32 + ksel;
      bf16x8 fa0 = *(const bf16x8*)&s_a[(wm+rsel)*LDK + kb];
      bf16x8 fa1 = *(const bf16x8*)&s_a[(wm+16+rsel)*LDK + kb];
      bf16x8 fb0 = *(const bf16x8*)&s_w[(wn+rsel)*LDK + kb];
      bf16x8 fb1 = *(const bf16x8*)&s_w[(wn+16+rsel)*LDK + kb];
      acc[0][0]=mfma16(fa0,fb0,acc[0][0]);
      acc[0][1]=mfma16(fa0,fb1,acc[0][1]);
      acc[1][0]=mfma16(fa1,fb0,acc[1][0]);
      acc[1][1]=mfma16(fa1,fb1,acc[1][1]);
    }
    __syncthreads();
  }

  #pragma unroll
  for (int i=0;i<2;++i){
    #pragma unroll
    for (int j=0;j<2;++j){
      int col = n0 + wn + j*16 + (lane&15);
      float bv = BIAS ? bias[col] : 0.0f;
      #pragma unroll
      for (int r=0;r<4;++r){
        int row = m0 + wm + i*16 + 4*(lane>>4) + r;
        float v = acc[i][j][r] + bv;
        if (ACT==1) v = silu_f(v);
        if (RESID) v += resid[(size_t)row*Nw + col];
        if (OBF) outb[(size_t)row*Nw + col] = (bf16)v;
        if (OF)  outf[(size_t)row*Nw + col] = v;
      }
    }
  }
}

// ---------------- fused edge MLP + segmented aggregation ----------------
// 128 edges/block, 512 threads, 64KB LDS (swizzled), in-register reduce.
__global__ __launch_bounds__(512, 4) void k_edge(
    const bf16* __restrict__ P, const bf16* __restrict__ w2t,
    const float* __restrict__ w1r, const float* __restrict__ b2,
    const int4* __restrict__ rec, float* __restrict__ aggr)
{
  __shared__ char smem[65536];
  char* s_m1 = smem;            // [128 rows][256B] swizzled bf16
  char* s_w2 = smem + 32768;    // [128 rows][256B] swizzled bf16
  int tid = threadIdx.x, lane = tid & 63, w = tid >> 6;
  int e0 = blockIdx.x * 128;

  // stage w2T (swizzled)
  #pragma unroll
  for (int it=0; it<4; ++it){
    int idx = tid + it*512;
    int r = idx >> 4, cb = (idx & 15)*16;
    *(bf16x8*)(s_w2 + swz(r, cb)) = *(const bf16x8*)((const char*)w2t + r*256 + cb);
  }

  // m1 = silu(PA[dst] + PB[src] + dist*w1r)   (b1 folded into P's bias)
  int cq = (tid & 15)*8;                  // column (elements), constant per thread
  f32x4 wr0 = *(const f32x4*)(w1r + cq);
  f32x4 wr1 = *(const f32x4*)(w1r + cq + 4);
  #pragma unroll
  for (int it=0; it<4; ++it){
    int e = (tid >> 4) + it*32;
    int4 rc = rec[e0 + e];
    int s = rc.x, d = rc.y;
    float dist = __int_as_float(rc.z);
    bf16x8 pa = *(const bf16x8*)(P + ((size_t)d << 8) + cq);
    bf16x8 pb = *(const bf16x8*)(P + ((size_t)s << 8) + 128 + cq);
    bf16x8 mm;
    #pragma unroll
    for (int j=0;j<4;++j){
      float pre = (float)pa[j] + (float)pb[j] + dist*wr0[j];
      mm[j] = (bf16)silu_f(pre);
    }
    #pragma unroll
    for (int j=0;j<4;++j){
      float pre = (float)pa[4+j] + (float)pb[4+j] + dist*wr1[j];
      mm[4+j] = (bf16)silu_f(pre);
    }
    *(bf16x8*)(s_m1 + swz(e, cq*2)) = mm;
  }
  __syncthreads();

  // GEMM: wave w owns edges [w*16, w*16+16), 128 output cols
  int rsel = lane & 15, hi = lane >> 4;
  f32x4 acc[8];
  #pragma unroll
  for (int n=0;n<8;++n)
    #pragma unroll
    for (int r=0;r<4;++r) acc[n][r]=0.f;
  #pragma unroll
  for (int ks=0;ks<4;++ks){
    int cb = ks*64 + hi*16;
    bf16x8 fa = *(const bf16x8*)(s_m1 + swz(w*16 + rsel, cb));
    #pragma unroll
    for (int n=0;n<8;++n){
      bf16x8 fb = *(const bf16x8*)(s_w2 + swz(n*16 + rsel, cb));
      acc[n] = mfma16(fa, fb, acc[n]);
    }
  }

  // in-register segmented reduce over sorted dst (4 consecutive edges/lane)
  int ebase = e0 + w*16 + hi*4;
  int d0 = rec[ebase+0].y, d1 = rec[ebase+1].y, d2 = rec[ebase+2].y, d3 = rec[ebase+3].y;
  int dw = __shfl(d0, 0);
  bool fastp = __all(d0==dw && d3==dw);
  #pragma unroll
  for (int n=0;n<8;++n){
    int col = n*16 + rsel;
    float bb = b2[col];
    float v0 = silu_f(acc[n][0] + bb);
    float v1 = silu_f(acc[n][1] + bb);
    float v2 = silu_f(acc[n][2] + bb);
    float v3 = silu_f(acc[n][3] + bb);
    if (fastp){
      float ssum = v0+v1+v2+v3;
      ssum += __shfl_down(ssum, 16);
      ssum += __shfl_down(ssum, 32);
      if (lane < 16) atomicAdd(&aggr[(size_t)dw*128 + col], ssum);
    } else {
      int cur = d0; float a = v0;
      if (d1 != cur){ atomicAdd(&aggr[(size_t)cur*128 + col], a); cur = d1; a = v1; } else a += v1;
      if (d2 != cur){ atomicAdd(&aggr[(size_t)cur*128 + col], a); cur = d2; a = v2; } else a += v2;
      if (d3 != cur){ atomicAdd(&aggr[(size_t)cur*128 + col], a); cur = d3; a = v3; } else a += v3;
      atomicAdd(&aggr[(size_t)cur*128 + col], a);
    }
  }
}

// ---------------- pooling + transformer (fused, fp32) ----------------
__device__ __forceinline__ int lbound(const int* a, int n, int key){
  int lo=0, hi=n;
  while (lo<hi){ int mid=(lo+hi)>>1; if (a[mid]<key) lo=mid+1; else hi=mid; }
  return lo;
}

__global__ __launch_bounds__(384) void k_pool_qkv(
    const float* __restrict__ h, const int* __restrict__ batch,
    const float* __restrict__ wq, const float* __restrict__ bq,
    float* __restrict__ gbuf, float* __restrict__ qkvb)
{
  __shared__ float sg[128];
  int gr = blockIdx.x, tid = threadIdx.x;
  if (tid < 128){
    int lo = lbound(batch, NN, gr), hi2 = lbound(batch, NN, gr+1);
    float s = 0.f;
    for (int n=lo;n<hi2;++n) s += h[(size_t)n*HH + tid];
    int c = hi2 - lo; if (c < 1) c = 1;
    s /= (float)c;
    sg[tid] = s; gbuf[gr*128 + tid] = s;
  }
  __syncthreads();
  float a = bq[tid];
  for (int k=0;k<128;++k) a += sg[k]*wq[k*384 + tid];
  qkvb[gr*384 + tid] = a;
}

__global__ __launch_bounds__(384) void k_qkv2(
    const float* __restrict__ g, const float* __restrict__ wq,
    const float* __restrict__ bq, float* __restrict__ qkvb)
{
  __shared__ float sg[128];
  int r = blockIdx.x, tid = threadIdx.x;
  if (tid < 128) sg[tid] = g[r*128 + tid];
  __syncthreads();
  float a = bq[tid];
  for (int k=0;k<128;++k) a += sg[k]*wq[k*384 + tid];
  qkvb[r*384 + tid] = a;
}

// attn + proj + ln1 + ff + ln2 (+cls) for one row
template<bool CLS>
__global__ __launch_bounds__(128) void k_tail(
    const float* __restrict__ qkv, const float* __restrict__ wo,
    const float* __restrict__ bo, const float* __restrict__ l1g,
    const float* __restrict__ l1b, const float* __restrict__ w1,
    const float* __restrict__ b1f, const float* __restrict__ w2,
    const float* __restrict__ b2f, const float* __restrict__ l2g,
    const float* __restrict__ l2b, float* __restrict__ gbuf,
    const float* __restrict__ cw1, const float* __restrict__ cb1,
    const float* __restrict__ cw2, const float* __restrict__ cb2,
    float* __restrict__ out)
{
  __shared__ float sq[128];
  __shared__ float ss[4][256];
  __shared__ float so[128];
  __shared__ float st[256];
  __shared__ float red[4];
  int r = blockIdx.x, tid = threadIdx.x;
  sq[tid] = qkv[r*384 + tid];
  __syncthreads();
  const float scale = 0.17677669529663687f;
  for (int i=tid; i<1024; i+=128){
    int hh = i >> 8, j = i & 255;
    const float* kr = qkv + j*384 + 128 + hh*32;
    const float* qr = sq + hh*32;
    float s=0;
    #pragma unroll
    for (int d=0;d<32;++d) s += qr[d]*kr[d];
    ss[hh][j] = s*scale;
  }
  __syncthreads();
  int hh = tid >> 5, sl = tid & 31;
  float m = -1e30f;
  #pragma unroll
  for (int q8=0;q8<8;++q8) m = fmaxf(m, ss[hh][sl + q8*32]);
  #pragma unroll
  for (int off=16; off; off>>=1) m = fmaxf(m, __shfl_xor(m, off, 32));
  float sum = 0.f;
  #pragma unroll
  for (int q8=0;q8<8;++q8){
    float e = __expf(ss[hh][sl+q8*32] - m);
    ss[hh][sl+q8*32] = e;
    sum += e;
  }
  #pragma unroll
  for (int off=16; off; off>>=1) sum += __shfl_xor(sum, off, 32);
  float inv = __builtin_amdgcn_rcpf(sum);
  __syncthreads();
  float accv = 0.f;
  for (int j=0;j<256;++j) accv += ss[hh][j]*qkv[j*384 + 256 + hh*32 + sl];
  so[tid] = accv*inv;
  __syncthreads();
  // proj + residual + ln1
  float a = bo[tid];
  for (int k=0;k<128;++k) a += so[k]*wo[k*128 + tid];
  float val = gbuf[r*128 + tid] + a;
  {
    float s = val, q = val*val;
    #pragma unroll
    for (int off=32; off; off>>=1){ s += __shfl_xor(s, off); q += __shfl_xor(q, off); }
    int lane = tid & 63, wv = tid >> 6;
    if (lane==0){ red[wv*2]=s; red[wv*2+1]=q; }
    __syncthreads();
    float S = red[0]+red[2], Q = red[1]+red[3];
    float mean = S*(1.0f/128.0f);
    float var = Q*(1.0f/128.0f) - mean*mean;
    float ninv = rsqrtf(var + 1e-5f);
    val = (val-mean)*ninv*l1g[tid] + l1b[tid];
  }
  sq[tid] = val;
  __syncthreads();
  // ff1
  float a0 = b1f[tid], a1 = b1f[tid+128];
  for (int k=0;k<128;++k){
    float gv = sq[k];
    a0 += gv*w1[k*256 + tid];
    a1 += gv*w1[k*256 + tid + 128];
  }
  st[tid]     = fmaxf(a0, 0.f);
  st[tid+128] = fmaxf(a1, 0.f);
  __syncthreads();
  // ff2 + residual + ln2
  float b = b2f[tid];
  for (int k=0;k<256;++k) b += st[k]*w2[k*128 + tid];
  float val2 = val + b;
  {
    float s = val2, q = val2*val2;
    #pragma unroll
    for (int off=32; off; off>>=1){ s += __shfl_xor(s, off); q += __shfl_xor(q, off); }
    int lane = tid & 63, wv = tid >> 6;
    __syncthreads();
    if (lane==0){ red[wv*2]=s; red[wv*2+1]=q; }
    __syncthreads();
    float S = red[0]+red[2], Q = red[1]+red[3];
    float mean = S*(1.0f/128.0f);
    float var = Q*(1.0f/128.0f) - mean*mean;
    float ninv = rsqrtf(var + 1e-5f);
    val2 = (val2-mean)*ninv*l2g[tid] + l2b[tid];
  }
  gbuf[r*128 + tid] = val2;
  if (CLS){
    so[tid] = val2;
    __syncthreads();
    if (tid < 64){
      float c = cb1[tid];
      for (int k=0;k<128;++k) c += so[k]*cw1[k*64 + tid];
      c = fmaxf(c, 0.f);
      float p = c * cw2[tid];
      #pragma unroll
      for (int off=32; off; off>>=1) p += __shfl_xor(p, off);
      if (tid==0) out[r] = p + cb2[0];
    }
  }
}

// ---------------- launch ----------------
extern "C" void kernel_launch(void* const* d_in, const int* in_sizes, int n_in,
                              void* d_out, int out_size, void* d_ws, size_t ws_size,
                              hipStream_t stream)
{
  (void)in_sizes; (void)n_in; (void)out_size; (void)ws_size;
  const float* x      = (const float*)d_in[0];
  const float* pos    = (const float*)d_in[1];
  const float* emb_w  = (const float*)d_in[2];
  const float* emb_b  = (const float*)d_in[3];
  const float* edge_w1= (const float*)d_in[4];
  const float* edge_b1= (const float*)d_in[5];
  const float* edge_w2= (const float*)d_in[6];
  const float* edge_b2= (const float*)d_in[7];
  const float* node_w1= (const float*)d_in[8];
  const float* node_b1= (const float*)d_in[9];
  const float* node_w2= (const float*)d_in[10];
  const float* node_b2= (const float*)d_in[11];
  const float* qkv_w  = (const float*)d_in[12];
  const float* qkv_b  = (const float*)d_in[13];
  const float* out_w  = (const float*)d_in[14];
  const float* out_b  = (const float*)d_in[15];
  const float* ln1_g  = (const float*)d_in[16];
  const float* ln1_b  = (const float*)d_in[17];
  const float* ln2_g  = (const float*)d_in[18];
  const float* ln2_b  = (const float*)d_in[19];
  const float* ff_w1  = (const float*)d_in[20];
  const float* ff_b1  = (const float*)d_in[21];
  const float* ff_w2  = (const float*)d_in[22];
  const float* ff_b2  = (const float*)d_in[23];
  const float* cls_w1 = (const float*)d_in[24];
  const float* cls_b1 = (const float*)d_in[25];
  const float* cls_w2 = (const float*)d_in[26];
  const float* cls_b2 = (const float*)d_in[27];
  const int* ei       = (const int*)d_in[28];
  const int* batch    = (const int*)d_in[29];
  float* out = (float*)d_out;

  uint8_t* wp = (uint8_t*)d_ws;
  auto take = [&](size_t nb)->void*{ void* r = wp; wp += (nb + 255) & ~(size_t)255; return r; };
  float* h      = (float*)take((size_t)NN*HH*4);
  bf16*  h_bf   = (bf16*) take((size_t)NN*HH*2);
  bf16*  P      = (bf16*) take((size_t)NN*256*2);
  float* aggr   = (float*)take((size_t)NN*HH*4);
  bf16*  u1     = (bf16*) take((size_t)NN*HH*2);
  int*   cnt    = (int*)  take((size_t)NN*4);
  int*   cursor = (int*)  take((size_t)NN*4);
  int4*  rec    = (int4*) take((size_t)EE*16);
  bf16*  wcatT  = (bf16*) take((size_t)3*256*128*2);
  bf16*  w2T    = (bf16*) take((size_t)3*128*128*2);
  bf16*  nw1T   = (bf16*) take((size_t)3*128*256*2);
  bf16*  nw2T   = (bf16*) take((size_t)3*128*128*2);
  float* bcat   = (float*)take((size_t)3*256*4);
  float* gbuf   = (float*)take((size_t)GG*HH*4);
  float* qkvb   = (float*)take((size_t)GG*384*4);

  dim3 b256(256);
  hipMemsetAsync(cnt, 0, (size_t)NN*4, stream);
  k_bcat<<<dim3(3), b256, 0, stream>>>(edge_b1, bcat);
  k_transpose_bf16<<<dim3(64,3), b256, 0, stream>>>(edge_w1,           wcatT,           128,128, 257*128, 256*128);
  k_transpose_bf16<<<dim3(64,3), b256, 0, stream>>>(edge_w1 + 128*128, wcatT + 128*128, 128,128, 257*128, 256*128);
  k_transpose_bf16<<<dim3(64,3), b256, 0, stream>>>(edge_w2,           w2T,             128,128, 128*128, 128*128);
  k_transpose_bf16<<<dim3(128,3), b256, 0, stream>>>(node_w1,          nw1T,            256,128, 256*128, 128*256);
  k_transpose_bf16<<<dim3(64,3), b256, 0, stream>>>(node_w2,           nw2T,            128,128, 128*128, 128*128);
  k_emb<<<dim3(NN*128/256), b256, 0, stream>>>(x, emb_w, emb_b, h, h_bf);
  k_hist<<<dim3(EE/256), b256, 0, stream>>>(ei + EE, cnt);
  k_scan<<<dim3(1), dim3(1024), 0, stream>>>(cnt, cursor, NN);
  k_scatter<<<dim3(EE/256), b256, 0, stream>>>(ei, pos, cursor, rec);

  for (int l=0;l<3;++l){
    // P = h @ [W1_dst | W1_src] + [b1|0]  -> bf16 [N][256]
    k_gemm<128,128,0,true,true,false,true,false><<<dim3(625,4), b256, 0, stream>>>(
      h_bf, nullptr, wcatT + (size_t)l*256*128, bcat + (size_t)l*256, nullptr, P, nullptr, 256);
    hipMemsetAsync(aggr, 0, (size_t)NN*128*4, stream);
    k_edge<<<dim3(EE/128), dim3(512), 0, stream>>>(P, w2T + (size_t)l*128*128,
      edge_w1 + ((size_t)l*257 + 256)*128, edge_b2 + (size_t)l*128, rec, aggr);
    // u1 = silu([h | aggr] @ node_w1 + b1)
    k_gemm<256,128,1,true,true,false,true,false><<<dim3(625,2), b256, 0, stream>>>(
      h_bf, aggr, nw1T + (size_t)l*128*256, node_b1 + (size_t)l*128, nullptr, u1, nullptr, 128);
    // h = h + (u1 @ node_w2 + b2)  (writes f32 h and bf16 h_bf)
    k_gemm<128,128,0,true,true,true,true,true><<<dim3(625,2), b256, 0, stream>>>(
      u1, nullptr, nw2T + (size_t)l*128*128, node_b2 + (size_t)l*128, h, h_bf, h, 128);
  }

  k_pool_qkv<<<dim3(GG), dim3(384), 0, stream>>>(h, batch, qkv_w, qkv_b, gbuf, qkvb);
  k_tail<false><<<dim3(GG), dim3(128), 0, stream>>>(qkvb, out_w, out_b,
    ln1_g, ln1_b, ff_w1, ff_b1, ff_w2, ff_b2, ln2_g, ln2_b, gbuf,
    nullptr, nullptr, nullptr, nullptr, nullptr);
  k_qkv2<<<dim3(GG), dim3(384), 0, stream>>>(gbuf, qkv_w + (size_t)128*384, qkv_b + 384, qkvb);
  k_tail<true><<<dim3(GG), dim3(128), 0, stream>>>(qkvb, out_w + (size_t)128*128, out_b + 128,
    ln1_g + 128, ln1_b + 128, ff_w1 + (size_t)128*256, ff_b1 + 256, ff_w2 + (size_t)256*128, ff_b2 + 128,
    ln2_g + 128, ln2_b + 128, gbuf, cls_w1, cls_b1, cls_w2, cls_b2, out);
}

// Round 3
// 853.647 us; speedup vs baseline: 1.1640x; 1.1640x over previous
//
#include <hip/hip_runtime.h>
#include <hip/hip_bf16.h>
#include <stdint.h>

#define NN 40000
#define EE 640000
#define GG 256
#define FFE 9
#define HH 128

typedef __bf16 bf16;
typedef __bf16 bf16x8 __attribute__((ext_vector_type(8)));
typedef float f32x4 __attribute__((ext_vector_type(4)));

__device__ __forceinline__ f32x4 mfma16(bf16x8 a, bf16x8 b, f32x4 c){
  return __builtin_amdgcn_mfma_f32_16x16x32_bf16(a, b, c, 0, 0, 0);
}
__device__ __forceinline__ float silu_f(float x){
  return x * __builtin_amdgcn_rcpf(1.0f + __expf(-x));
}
// byte-offset XOR swizzle for [row][256B] LDS tiles
__device__ __forceinline__ int swz(int row, int cb){
  return row*256 + (cb ^ ((row & 7) << 4));
}

// ---------------- merged prep: weight transposes + bcat + cnt zero + embedding ----------------
__global__ __launch_bounds__(256) void k_prep(
    const float* __restrict__ edge_w1, const float* __restrict__ edge_w2,
    const float* __restrict__ node_w1, const float* __restrict__ node_w2,
    const float* __restrict__ edge_b1,
    const float* __restrict__ x, const float* __restrict__ emb_w,
    const float* __restrict__ emb_b,
    bf16* __restrict__ wcatT, bf16* __restrict__ w2T,
    bf16* __restrict__ nw1T, bf16* __restrict__ nw2T,
    float* __restrict__ bcat, float* __restrict__ h, bf16* __restrict__ h_bf,
    int* __restrict__ cnt)
{
  int b = blockIdx.x, tid = threadIdx.x;
  if (b < 192){                 // wcat part A: [n][k] <- edge_w1 rows 0..127
    int l = b/64; int t2 = (b%64)*256 + tid;
    int n = t2 >> 7, k = t2 & 127;
    wcatT[(size_t)l*32768 + n*128 + k] = (bf16)edge_w1[(size_t)l*32896 + k*128 + n];
  } else if (b < 384){          // wcat part B: edge_w1 rows 128..255
    int lb = b - 192; int l = lb/64; int t2 = (lb%64)*256 + tid;
    int n = t2 >> 7, k = t2 & 127;
    wcatT[(size_t)l*32768 + 16384 + n*128 + k] = (bf16)edge_w1[(size_t)l*32896 + (128+k)*128 + n];
  } else if (b < 576){          // w2T
    int lb = b - 384; int l = lb/64; int t2 = (lb%64)*256 + tid;
    int n = t2 >> 7, k = t2 & 127;
    w2T[(size_t)l*16384 + n*128 + k] = (bf16)edge_w2[(size_t)l*16384 + k*128 + n];
  } else if (b < 960){          // nw1T [128][256]
    int lb = b - 576; int l = lb/128; int t2 = (lb%128)*256 + tid;
    int n = t2 >> 8, k = t2 & 255;
    nw1T[(size_t)l*32768 + n*256 + k] = (bf16)node_w1[(size_t)l*32768 + k*128 + n];
  } else if (b < 1152){         // nw2T
    int lb = b - 960; int l = lb/64; int t2 = (lb%64)*256 + tid;
    int n = t2 >> 7, k = t2 & 127;
    nw2T[(size_t)l*16384 + n*128 + k] = (bf16)node_w2[(size_t)l*16384 + k*128 + n];
  } else if (b < 1155){         // bcat
    int l = b - 1152;
    bcat[l*256 + tid] = (tid < 128) ? edge_b1[l*128 + tid] : 0.0f;
  } else if (b < 1312){         // cnt zero
    int i = (b - 1155)*256 + tid;
    if (i < NN) cnt[i] = 0;
  } else {                      // embedding: 20000 blocks
    int idx = (b - 1312)*256 + tid;
    int n = idx >> 7, f = idx & 127;
    float s = emb_b[f];
    const float* xr = x + n*FFE;
    #pragma unroll
    for (int k=0;k<FFE;++k) s += xr[k]*emb_w[k*HH + f];
    h[idx] = s;
    h_bf[idx] = (bf16)s;
  }
}

// ---------------- counting sort by dst ----------------
__global__ __launch_bounds__(256) void k_hist(const int* __restrict__ dst, int* __restrict__ cnt){
  int e = blockIdx.x*256 + threadIdx.x;
  if (e < EE) atomicAdd(&cnt[dst[e]], 1);
}

__global__ __launch_bounds__(1024) void k_scan(const int* __restrict__ cnt, int* __restrict__ cursor, int n){
  __shared__ int s_wsum[16];
  __shared__ int s_run;
  int tid = threadIdx.x, lane = tid & 63, wv = tid >> 6;
  if (tid == 0) s_run = 0;
  __syncthreads();
  for (int base=0; base<n; base+=4096){
    int i = base + tid*4;
    int c0 = (i  <n)? cnt[i  ] : 0;
    int c1 = (i+1<n)? cnt[i+1] : 0;
    int c2 = (i+2<n)? cnt[i+2] : 0;
    int c3 = (i+3<n)? cnt[i+3] : 0;
    int t0 = c0, t1 = t0+c1, t2 = t1+c2, t3 = t2+c3;
    int xx = t3;
    #pragma unroll
    for (int off=1; off<64; off<<=1){ int t = __shfl_up(xx, off); if (lane>=off) xx += t; }
    if (lane==63) s_wsum[wv] = xx;
    __syncthreads();
    if (wv==0 && lane<16){
      int y = s_wsum[lane];
      #pragma unroll
      for (int off=1; off<16; off<<=1){ int t = __shfl_up(y, off, 16); if (lane>=off) y += t; }
      s_wsum[lane] = y;
    }
    __syncthreads();
    int woff = wv ? s_wsum[wv-1] : 0;
    int run = s_run;
    int eb = run + woff + xx - t3;
    if (i  <n) cursor[i  ] = eb;
    if (i+1<n) cursor[i+1] = eb + t0;
    if (i+2<n) cursor[i+2] = eb + t1;
    if (i+3<n) cursor[i+3] = eb + t2;
    __syncthreads();
    if (tid==0) s_run = run + s_wsum[15];
    __syncthreads();
  }
}

__global__ __launch_bounds__(256) void k_scatter(
    const int* __restrict__ ei, const float* __restrict__ pos,
    int* __restrict__ cursor, int4* __restrict__ rec)
{
  int e = blockIdx.x*256 + threadIdx.x;
  if (e >= EE) return;
  int s = ei[e], d = ei[EE + e];
  int p = atomicAdd(&cursor[d], 1);
  float dx = pos[d*3+0]-pos[s*3+0];
  float dy = pos[d*3+1]-pos[s*3+1];
  float dz = pos[d*3+2]-pos[s*3+2];
  int4 rc; rc.x = s; rc.y = d; rc.z = __float_as_int(sqrtf(dx*dx+dy*dy+dz*dz)); rc.w = 0;
  rec[p] = rc;
}

// ---------------- 128x64-tile bf16 MFMA GEMM ----------------
// out = act(A @ WT' + bias) (+resid); WT stored [Nw][KTOT] bf16.
// A: first K1 cols from a1 (bf16 if A1BF else f32), rest from a2 (f32).
// ZAGGR: blocks with blockIdx.y==0 also zero aggr rows [m0, m0+128).
template<int KTOT, int K1, int ACT, bool A1BF, bool BIAS, bool RESID, bool OBF, bool OF, bool ZAGGR>
__global__ __launch_bounds__(256) void k_gemm(
    const void* __restrict__ a1v, const float* __restrict__ a2,
    const bf16* __restrict__ wt, const float* __restrict__ bias,
    const float* __restrict__ resid, bf16* __restrict__ outb,
    float* __restrict__ outf, int Nw, float* __restrict__ aggr)
{
  constexpr int LDK = 136;
  __shared__ bf16 s_a[128*LDK];
  __shared__ bf16 s_w[64*LDK];
  int tid = threadIdx.x, lane = tid & 63, w = tid >> 6;
  int m0 = blockIdx.x*128, n0 = blockIdx.y*64;
  if (ZAGGR && blockIdx.y == 0){
    int nrows = NN - m0; if (nrows > 128) nrows = 128;
    f32x4 z = {0.f,0.f,0.f,0.f};
    for (int i = tid; i < nrows*32; i += 256)
      *(f32x4*)(aggr + (size_t)m0*128 + (size_t)i*4) = z;
  }
  f32x4 acc[2][4];
  #pragma unroll
  for (int i=0;i<2;++i)
    #pragma unroll
    for (int j=0;j<4;++j)
      #pragma unroll
      for (int r=0;r<4;++r) acc[i][j][r]=0.f;
  int rsel = lane & 15, ksel = (lane>>4)*8;
  int wm = w*32;

  for (int kh=0; kh<KTOT; kh+=128){
    #pragma unroll
    for (int it=0; it<8; ++it){          // stage A: 128 rows x 128 k
      int idx = tid + it*256;
      int row = idx >> 4, col = (idx & 15)*8;
      int gc = kh + col;
      int grow = m0 + row; if (grow > NN-1) grow = NN-1;
      bf16x8 vv;
      if (gc < K1){
        if (A1BF){
          vv = *(const bf16x8*)((const bf16*)a1v + (size_t)grow*K1 + gc);
        } else {
          const float* srcp = (const float*)a1v + (size_t)grow*K1 + gc;
          f32x4 u0 = *(const f32x4*)srcp;
          f32x4 u1 = *(const f32x4*)(srcp+4);
          vv[0]=(bf16)u0[0]; vv[1]=(bf16)u0[1]; vv[2]=(bf16)u0[2]; vv[3]=(bf16)u0[3];
          vv[4]=(bf16)u1[0]; vv[5]=(bf16)u1[1]; vv[6]=(bf16)u1[2]; vv[7]=(bf16)u1[3];
        }
      } else {
        const float* srcp = a2 + (size_t)grow*(KTOT-K1) + (gc-K1);
        f32x4 u0 = *(const f32x4*)srcp;
        f32x4 u1 = *(const f32x4*)(srcp+4);
        vv[0]=(bf16)u0[0]; vv[1]=(bf16)u0[1]; vv[2]=(bf16)u0[2]; vv[3]=(bf16)u0[3];
        vv[4]=(bf16)u1[0]; vv[5]=(bf16)u1[1]; vv[6]=(bf16)u1[2]; vv[7]=(bf16)u1[3];
      }
      *(bf16x8*)&s_a[row*LDK + col] = vv;
    }
    #pragma unroll
    for (int it=0; it<4; ++it){          // stage W: 64 rows x 128 k
      int idx = tid + it*256;
      int row = idx >> 4, col = (idx & 15)*8;
      *(bf16x8*)&s_w[row*LDK + col] = *(const bf16x8*)(wt + (size_t)(n0+row)*KTOT + kh + col);
    }
    __syncthreads();
    #pragma unroll
    for (int ks=0; ks<4; ++ks){
      int kb = ks*32 + ksel;
      bf16x8 fa0 = *(const bf16x8*)&s_a[(wm+rsel)*LDK + kb];
      bf16x8 fa1 = *(const bf16x8*)&s_a[(wm+16+rsel)*LDK + kb];
      #pragma unroll
      for (int j=0;j<4;++j){
        bf16x8 fb = *(const bf16x8*)&s_w[(j*16+rsel)*LDK + kb];
        acc[0][j]=mfma16(fa0,fb,acc[0][j]);
        acc[1][j]=mfma16(fa1,fb,acc[1][j]);
      }
    }
    __syncthreads();
  }

  #pragma unroll
  for (int i=0;i<2;++i){
    #pragma unroll
    for (int j=0;j<4;++j){
      int col = n0 + j*16 + rsel;
      float bv = BIAS ? bias[col] : 0.0f;
      #pragma unroll
      for (int r=0;r<4;++r){
        int row = m0 + wm + i*16 + 4*(lane>>4) + r;
        if (row < NN){
          float v = acc[i][j][r] + bv;
          if (ACT==1) v = silu_f(v);
          if (RESID) v += resid[(size_t)row*Nw + col];
          if (OBF) outb[(size_t)row*Nw + col] = (bf16)v;
          if (OF)  outf[(size_t)row*Nw + col] = v;
        }
      }
    }
  }
}

// ---------------- fused edge MLP + segmented aggregation ----------------
// 128 edges/block, 512 threads, 64KB LDS; run-length reduce with
// store-vs-atomic (atomics only for runs touching a 32-edge window edge).
__global__ __launch_bounds__(512, 4) void k_edge(
    const bf16* __restrict__ P, const bf16* __restrict__ w2t,
    const float* __restrict__ w1r, const float* __restrict__ b2,
    const int4* __restrict__ rec, float* __restrict__ aggr)
{
  __shared__ char smem[65536];
  char* s_m1 = smem;            // bf16 [128 rows][256B] swizzled
  char* s_w2 = smem + 32768;    // bf16 [128 rows][256B] swizzled
  int tid = threadIdx.x, lane = tid & 63, w = tid >> 6;
  // XCD-chunked block swizzle (5000 % 8 == 0 -> bijective)
  int bid = blockIdx.x;
  int swb = (bid & 7) * (EE/128/8) + (bid >> 3);
  int e0 = swb * 128;

  // stage w2T (swizzled)
  #pragma unroll
  for (int it=0; it<4; ++it){
    int idx = tid + it*512;
    int r = idx >> 4, cb = (idx & 15)*16;
    *(bf16x8*)(s_w2 + swz(r, cb)) = *(const bf16x8*)((const char*)w2t + r*256 + cb);
  }

  // m1 = silu(PA[dst] + PB[src] + dist*w1r)  (b1 folded into P bias)
  int cq = (tid & 15)*8;
  int er = tid >> 4;           // 0..31
  int4 rc[4];
  #pragma unroll
  for (int it=0; it<4; ++it) rc[it] = rec[e0 + er + it*32];
  bf16x8 pa[4], pb[4];
  #pragma unroll
  for (int it=0; it<4; ++it){
    pa[it] = *(const bf16x8*)(P + ((size_t)rc[it].y << 8) + cq);
    pb[it] = *(const bf16x8*)(P + ((size_t)rc[it].x << 8) + 128 + cq);
  }
  f32x4 wr0 = *(const f32x4*)(w1r + cq);
  f32x4 wr1 = *(const f32x4*)(w1r + cq + 4);
  #pragma unroll
  for (int it=0; it<4; ++it){
    float dist = __int_as_float(rc[it].z);
    bf16x8 mm;
    #pragma unroll
    for (int j=0;j<4;++j){
      float pre = (float)pa[it][j] + (float)pb[it][j] + dist*wr0[j];
      mm[j] = (bf16)silu_f(pre);
    }
    #pragma unroll
    for (int j=0;j<4;++j){
      float pre = (float)pa[it][4+j] + (float)pb[it][4+j] + dist*wr1[j];
      mm[4+j] = (bf16)silu_f(pre);
    }
    *(bf16x8*)(s_m1 + swz(er + it*32, cq*2)) = mm;
  }
  __syncthreads();

  // GEMM: wave w owns edges [w*16, w*16+16), 128 output cols
  int rsel = lane & 15, hi = lane >> 4;
  f32x4 acc[8];
  #pragma unroll
  for (int n=0;n<8;++n)
    #pragma unroll
    for (int r=0;r<4;++r) acc[n][r]=0.f;
  #pragma unroll
  for (int ks=0;ks<4;++ks){
    int cb = ks*64 + hi*16;
    bf16x8 fa = *(const bf16x8*)(s_m1 + swz(w*16 + rsel, cb));
    #pragma unroll
    for (int n=0;n<8;++n){
      bf16x8 fb = *(const bf16x8*)(s_w2 + swz(n*16 + rsel, cb));
      acc[n] = mfma16(fa, fb, acc[n]);
    }
  }
  __syncthreads();   // all LDS reads done before m2 overwrites smem

  // m2 = silu(acc + b2) -> rotated f32 LDS [128 rows][128 cols]
  float* S = (float*)smem;
  #pragma unroll
  for (int n=0;n<8;++n){
    int col = n*16 + rsel;
    float bb = b2[col];
    #pragma unroll
    for (int r=0;r<4;++r){
      int row = w*16 + 4*hi + r;
      S[row*128 + ((col + row) & 127)] = silu_f(acc[n][r] + bb);
    }
  }
  __syncthreads();

  // segmented walk: 512 threads = 128 cols x 4 windows of 32 edges
  int col = tid & 127, q = tid >> 7;
  int r0 = q*32;
  int g0 = e0 + r0;
  int prevd = (g0 == 0) ? -1 : rec[g0-1].y;
  int nextd = (g0 + 32 >= EE) ? -1 : rec[g0+32].y;
  float a = 0.f; int cur = rec[g0].y; bool openL = (cur == prevd);
  #pragma unroll 4
  for (int i=0;i<32;++i){
    float v = S[(r0+i)*128 + ((col + r0 + i) & 127)];
    int d = rec[g0+i].y;
    if (d != cur){
      if (openL) atomicAdd(&aggr[(size_t)cur*128 + col], a);
      else       aggr[(size_t)cur*128 + col] = a;
      openL = false; a = v; cur = d;
    } else a += v;
  }
  if (openL || cur == nextd) atomicAdd(&aggr[(size_t)cur*128 + col], a);
  else                       aggr[(size_t)cur*128 + col] = a;
}

// ---------------- pooling + transformer (fp32) ----------------
__device__ __forceinline__ int lbound(const int* a, int n, int key){
  int lo=0, hi=n;
  while (lo<hi){ int mid=(lo+hi)>>1; if (a[mid]<key) lo=mid+1; else hi=mid; }
  return lo;
}

__global__ __launch_bounds__(384) void k_pool_qkv(
    const float* __restrict__ h, const int* __restrict__ batch,
    const float* __restrict__ wq, const float* __restrict__ bq,
    float* __restrict__ gbuf, float* __restrict__ qkvb)
{
  __shared__ float sg[128];
  int gr = blockIdx.x, tid = threadIdx.x;
  if (tid < 128){
    int lo = lbound(batch, NN, gr), hi2 = lbound(batch, NN, gr+1);
    float s = 0.f;
    for (int n=lo;n<hi2;++n) s += h[(size_t)n*HH + tid];
    int c = hi2 - lo; if (c < 1) c = 1;
    s /= (float)c;
    sg[tid] = s; gbuf[gr*128 + tid] = s;
  }
  __syncthreads();
  float a = bq[tid];
  for (int k=0;k<128;++k) a += sg[k]*wq[k*384 + tid];
  qkvb[gr*384 + tid] = a;
}

// attn + proj + ln1 + ff + ln2, then MODE0: next-layer qkv; MODE1: classifier
template<int MODE>
__global__ __launch_bounds__(128) void k_tail(
    const float* __restrict__ qkv, const float* __restrict__ wo,
    const float* __restrict__ bo, const float* __restrict__ l1g,
    const float* __restrict__ l1b, const float* __restrict__ w1,
    const float* __restrict__ b1f, const float* __restrict__ w2,
    const float* __restrict__ b2f, const float* __restrict__ l2g,
    const float* __restrict__ l2b, float* __restrict__ gbuf,
    const float* __restrict__ wq2, const float* __restrict__ bq2,
    float* __restrict__ qkvb2,
    const float* __restrict__ cw1, const float* __restrict__ cb1,
    const float* __restrict__ cw2, const float* __restrict__ cb2,
    float* __restrict__ out)
{
  __shared__ float sq[128];
  __shared__ float ss[4][256];
  __shared__ float so[128];
  __shared__ float st[256];
  __shared__ float red[4];
  int r = blockIdx.x, tid = threadIdx.x;
  sq[tid] = qkv[r*384 + tid];
  __syncthreads();
  const float scale = 0.17677669529663687f;
  for (int i=tid; i<1024; i+=128){
    int hh = i >> 8, j = i & 255;
    const float* kr = qkv + j*384 + 128 + hh*32;
    const float* qr = sq + hh*32;
    float s=0;
    #pragma unroll
    for (int d=0;d<32;++d) s += qr[d]*kr[d];
    ss[hh][j] = s*scale;
  }
  __syncthreads();
  int hh = tid >> 5, sl = tid & 31;
  float m = -1e30f;
  #pragma unroll
  for (int q8=0;q8<8;++q8) m = fmaxf(m, ss[hh][sl + q8*32]);
  #pragma unroll
  for (int off=16; off; off>>=1) m = fmaxf(m, __shfl_xor(m, off, 32));
  float sum = 0.f;
  #pragma unroll
  for (int q8=0;q8<8;++q8){
    float e = __expf(ss[hh][sl+q8*32] - m);
    ss[hh][sl+q8*32] = e;
    sum += e;
  }
  #pragma unroll
  for (int off=16; off; off>>=1) sum += __shfl_xor(sum, off, 32);
  float inv = __builtin_amdgcn_rcpf(sum);
  __syncthreads();
  float accv = 0.f;
  for (int j=0;j<256;++j) accv += ss[hh][j]*qkv[j*384 + 256 + hh*32 + sl];
  so[tid] = accv*inv;
  __syncthreads();
  float a = bo[tid];
  for (int k=0;k<128;++k) a += so[k]*wo[k*128 + tid];
  float val = gbuf[r*128 + tid] + a;
  {
    float s = val, q = val*val;
    #pragma unroll
    for (int off=32; off; off>>=1){ s += __shfl_xor(s, off); q += __shfl_xor(q, off); }
    int lane = tid & 63, wv = tid >> 6;
    if (lane==0){ red[wv*2]=s; red[wv*2+1]=q; }
    __syncthreads();
    float S = red[0]+red[2], Q = red[1]+red[3];
    float mean = S*(1.0f/128.0f);
    float var = Q*(1.0f/128.0f) - mean*mean;
    float ninv = rsqrtf(var + 1e-5f);
    val = (val-mean)*ninv*l1g[tid] + l1b[tid];
  }
  sq[tid] = val;
  __syncthreads();
  float a0 = b1f[tid], a1 = b1f[tid+128];
  for (int k=0;k<128;++k){
    float gv = sq[k];
    a0 += gv*w1[k*256 + tid];
    a1 += gv*w1[k*256 + tid + 128];
  }
  st[tid]     = fmaxf(a0, 0.f);
  st[tid+128] = fmaxf(a1, 0.f);
  __syncthreads();
  float b = b2f[tid];
  for (int k=0;k<256;++k) b += st[k]*w2[k*128 + tid];
  float val2 = val + b;
  {
    float s = val2, q = val2*val2;
    #pragma unroll
    for (int off=32; off; off>>=1){ s += __shfl_xor(s, off); q += __shfl_xor(q, off); }
    int lane = tid & 63, wv = tid >> 6;
    __syncthreads();
    if (lane==0){ red[wv*2]=s; red[wv*2+1]=q; }
    __syncthreads();
    float S = red[0]+red[2], Q = red[1]+red[3];
    float mean = S*(1.0f/128.0f);
    float var = Q*(1.0f/128.0f) - mean*mean;
    float ninv = rsqrtf(var + 1e-5f);
    val2 = (val2-mean)*ninv*l2g[tid] + l2b[tid];
  }
  gbuf[r*128 + tid] = val2;
  if (MODE == 0){
    sq[tid] = val2;
    __syncthreads();
    float q0 = bq2[tid], q1 = bq2[tid+128], q2 = bq2[tid+256];
    for (int k=0;k<128;++k){
      float gv = sq[k];
      const float* wr = wq2 + k*384;
      q0 += gv*wr[tid]; q1 += gv*wr[tid+128]; q2 += gv*wr[tid+256];
    }
    qkvb2[r*384+tid]=q0; qkvb2[r*384+tid+128]=q1; qkvb2[r*384+tid+256]=q2;
  }
  if (MODE == 1){
    so[tid] = val2;
    __syncthreads();
    if (tid < 64){
      float c = cb1[tid];
      for (int k=0;k<128;++k) c += so[k]*cw1[k*64 + tid];
      c = fmaxf(c, 0.f);
      float p = c * cw2[tid];
      #pragma unroll
      for (int off=32; off; off>>=1) p += __shfl_xor(p, off);
      if (tid==0) out[r] = p + cb2[0];
    }
  }
}

// ---------------- launch ----------------
extern "C" void kernel_launch(void* const* d_in, const int* in_sizes, int n_in,
                              void* d_out, int out_size, void* d_ws, size_t ws_size,
                              hipStream_t stream)
{
  (void)in_sizes; (void)n_in; (void)out_size; (void)ws_size;
  const float* x      = (const float*)d_in[0];
  const float* pos    = (const float*)d_in[1];
  const float* emb_w  = (const float*)d_in[2];
  const float* emb_b  = (const float*)d_in[3];
  const float* edge_w1= (const float*)d_in[4];
  const float* edge_b1= (const float*)d_in[5];
  const float* edge_w2= (const float*)d_in[6];
  const float* edge_b2= (const float*)d_in[7];
  const float* node_w1= (const float*)d_in[8];
  const float* node_b1= (const float*)d_in[9];
  const float* node_w2= (const float*)d_in[10];
  const float* node_b2= (const float*)d_in[11];
  const float* qkv_w  = (const float*)d_in[12];
  const float* qkv_b  = (const float*)d_in[13];
  const float* out_w  = (const float*)d_in[14];
  const float* out_b  = (const float*)d_in[15];
  const float* ln1_g  = (const float*)d_in[16];
  const float* ln1_b  = (const float*)d_in[17];
  const float* ln2_g  = (const float*)d_in[18];
  const float* ln2_b  = (const float*)d_in[19];
  const float* ff_w1  = (const float*)d_in[20];
  const float* ff_b1  = (const float*)d_in[21];
  const float* ff_w2  = (const float*)d_in[22];
  const float* ff_b2  = (const float*)d_in[23];
  const float* cls_w1 = (const float*)d_in[24];
  const float* cls_b1 = (const float*)d_in[25];
  const float* cls_w2 = (const float*)d_in[26];
  const float* cls_b2 = (const float*)d_in[27];
  const int* ei       = (const int*)d_in[28];
  const int* batch    = (const int*)d_in[29];
  float* out = (float*)d_out;

  uint8_t* wp = (uint8_t*)d_ws;
  auto take = [&](size_t nb)->void*{ void* r = wp; wp += (nb + 255) & ~(size_t)255; return r; };
  float* h      = (float*)take((size_t)NN*HH*4);
  bf16*  h_bf   = (bf16*) take((size_t)NN*HH*2);
  bf16*  P      = (bf16*) take((size_t)NN*256*2);
  float* aggr   = (float*)take((size_t)NN*HH*4);
  bf16*  u1     = (bf16*) take((size_t)NN*HH*2);
  int*   cnt    = (int*)  take((size_t)NN*4);
  int*   cursor = (int*)  take((size_t)NN*4);
  int4*  rec    = (int4*) take((size_t)EE*16);
  bf16*  wcatT  = (bf16*) take((size_t)3*256*128*2);
  bf16*  w2T    = (bf16*) take((size_t)3*128*128*2);
  bf16*  nw1T   = (bf16*) take((size_t)3*128*256*2);
  bf16*  nw2T   = (bf16*) take((size_t)3*128*128*2);
  float* bcat   = (float*)take((size_t)3*256*4);
  float* gbuf   = (float*)take((size_t)GG*HH*4);
  float* qkvb   = (float*)take((size_t)GG*384*4);
  float* qkvb2  = (float*)take((size_t)GG*384*4);

  dim3 b256(256);
  k_prep<<<dim3(21312), b256, 0, stream>>>(edge_w1, edge_w2, node_w1, node_w2,
    edge_b1, x, emb_w, emb_b, wcatT, w2T, nw1T, nw2T, bcat, h, h_bf, cnt);
  k_hist<<<dim3(EE/256), b256, 0, stream>>>(ei + EE, cnt);
  k_scan<<<dim3(1), dim3(1024), 0, stream>>>(cnt, cursor, NN);
  k_scatter<<<dim3(EE/256), b256, 0, stream>>>(ei, pos, cursor, rec);

  for (int l=0;l<3;++l){
    // P = h @ [W1_dst | W1_src] + [b1|0] -> bf16 [N][256]; y==0 blocks zero aggr
    k_gemm<128,128,0,true,true,false,true,false,true><<<dim3(313,4), b256, 0, stream>>>(
      h_bf, nullptr, wcatT + (size_t)l*256*128, bcat + (size_t)l*256, nullptr, P, nullptr, 256, aggr);
    k_edge<<<dim3(EE/128), dim3(512), 0, stream>>>(P, w2T + (size_t)l*128*128,
      edge_w1 + ((size_t)l*257 + 256)*128, edge_b2 + (size_t)l*128, rec, aggr);
    // u1 = silu([h | aggr] @ node_w1 + b1)
    k_gemm<256,128,1,true,true,false,true,false,false><<<dim3(313,2), b256, 0, stream>>>(
      h_bf, aggr, nw1T + (size_t)l*128*256, node_b1 + (size_t)l*128, nullptr, u1, nullptr, 128, nullptr);
    // h = h + (u1 @ node_w2 + b2)  (writes f32 h and bf16 h_bf)
    k_gemm<128,128,0,true,true,true,true,true,false><<<dim3(313,2), b256, 0, stream>>>(
      u1, nullptr, nw2T + (size_t)l*128*128, node_b2 + (size_t)l*128, h, h_bf, h, 128, nullptr);
  }

  k_pool_qkv<<<dim3(GG), dim3(384), 0, stream>>>(h, batch, qkv_w, qkv_b, gbuf, qkvb);
  k_tail<0><<<dim3(GG), dim3(128), 0, stream>>>(qkvb, out_w, out_b,
    ln1_g, ln1_b, ff_w1, ff_b1, ff_w2, ff_b2, ln2_g, ln2_b, gbuf,
    qkv_w + (size_t)128*384, qkv_b + 384, qkvb2,
    nullptr, nullptr, nullptr, nullptr, nullptr);
  k_tail<1><<<dim3(GG), dim3(128), 0, stream>>>(qkvb2, out_w + (size_t)128*128, out_b + 128,
    ln1_g + 128, ln1_b + 128, ff_w1 + (size_t)128*256, ff_b1 + 256,
    ff_w2 + (size_t)256*128, ff_b2 + 128, ln2_g + 128, ln2_b + 128, gbuf,
    nullptr, nullptr, nullptr,
    cls_w1, cls_b1, cls_w2, cls_b2, out);
}